// Round 3
// baseline (227.254 us; speedup 1.0000x reference)
//
#include <hip/hip_runtime.h>
#include <math.h>

// Problem constants
#define NB 128     // batch
#define NC 128     // channels
#define NN 170     // nodes
#define NT 12      // length
#define MP 176     // P row stride (halfs); 176*2B = 352B
#define XSTR 176   // xs row stride per (b,c) (halfs): pad cols [170,176) zeroed by k1
#define MEST 192   // Est padded rows (12 col-tiles of 16)

// Workspace regions (halfs)
#define EST_SZ ((size_t)MEST * NC)          //    24,576 halfs (48 KB)
#define XS_SZ  ((size_t)NB * NC * XSTR)     // 2,883,584 halfs (5.8 MB)
#define P_SZ   ((size_t)NB * NN * MP)       // 3,829,760 halfs (7.3 MB)

// MFMA fragment / accumulator types (16x16x32 f16: 8 halfs per operand lane)
typedef _Float16 h8 __attribute__((ext_vector_type(8)));
typedef __fp16   g2 __attribute__((ext_vector_type(2)));  // cvt_pkrtz return type
typedef float    f4 __attribute__((ext_vector_type(4)));

// tanh via hw exp+rcp: ~6 VALU ops vs ~30+ for libm tanhf. rel err ~1e-6.
__device__ __forceinline__ float fast_tanh(float x) {
    float cx = fminf(fmaxf(x, -15.f), 15.f);        // avoid inf/inf
    float e  = __expf(2.f * cx);                    // v_exp_f32
    return (e - 1.f) * __builtin_amdgcn_rcpf(e + 1.f);
}

// ---------------------------------------------------------------------------
// K1 (fused tsum + Est transpose):
//  blocks [0,5440):  xs[b][c][n] = f16(sum_t x[b][c][n][t]), plus zero the
//                    pad cols [170,176) so the fused kernel can h8-load rows.
//  blocks [5440,5536): Est[m][c] = f16(Es[c][m]), zero rows m in [170,192).
// Barrier-free streaming at full occupancy — carries the 133.7 MB x read.
// ---------------------------------------------------------------------------
__global__ __launch_bounds__(256) void k1_tsum_est(const float* __restrict__ x,
                                                   const float* __restrict__ Es,
                                                   _Float16* __restrict__ xs,
                                                   _Float16* __restrict__ Est) {
    const int bid = blockIdx.x;
    if (bid < 5440) {
        unsigned tid = bid * 256u + threadIdx.x;    // [0, 128*128*85)
        unsigned bc = tid / 85u;                    // (b*NC + c)
        unsigned p  = tid - bc * 85u;               // n-pair index, n = 2p
        const float4* q = reinterpret_cast<const float4*>(
            x + (size_t)bc * (NN * NT) + (size_t)p * (2 * NT));
        float4 f0 = q[0], f1 = q[1], f2 = q[2];     // n = 2p
        float4 f3 = q[3], f4v = q[4], f5 = q[5];    // n = 2p+1
        float s0 = ((f0.x + f0.y) + (f0.z + f0.w))
                 + ((f1.x + f1.y) + (f1.z + f1.w))
                 + ((f2.x + f2.y) + (f2.z + f2.w));
        float s1 = ((f3.x + f3.y) + (f3.z + f3.w))
                 + ((f4v.x + f4v.y) + (f4v.z + f4v.w))
                 + ((f5.x + f5.y) + (f5.z + f5.w));
        g2 pk = __builtin_amdgcn_cvt_pkrtz(s0, s1);
        *reinterpret_cast<g2*>(xs + (size_t)bc * XSTR + 2 * p) = pk;  // 4B store
        if (p < 3)  // zero pad cols 170..175 (3 g2 slots per row)
            *reinterpret_cast<unsigned*>(xs + (size_t)bc * XSTR + 170 + 2 * p) = 0u;
    } else {
        int idx = (bid - 5440) * 256 + threadIdx.x; // [0, 192*128)
        int m = idx >> 7, c = idx & 127;
        Est[idx] = (m < NN) ? (_Float16)Es[c * NN + m] : (_Float16)0.f;
    }
}

// ---------------------------------------------------------------------------
// K23 (mega-fused): per (half h, batch b):
//   1) stage xs[b] transposed -> At[192 n][128 c] f16 in LDS (XOR-swizzled)
//   2) GEMM1: EdL[n][m] = tanh( sum_c At[n][c] * Est[m][c] )  -- LDS only
//   3) GEMM2: scores[n][k] = sum_m EdL[n][m]*EdL[k][m] for n in the block's
//      96-row half, all 192 k (pad rows/cols are exact zeros)
//   4) relu+scale -> Sc (f32, 48 rows x 2 rounds, aliases At) -> row softmax
//      (k3's proven wave-parallel pattern) -> P f16.
// Grid (2,128) = 256 blocks = 1 per CU (LDS 120 KB caps occupancy at 1).
// MFMA pattern is the HW-verified A·B^T family used by the passing round-2
// k2/k3 (A-frag rows, B-frag rows, D: col=lane&15, row=quad*4+reg).
// XOR swizzle: group' = group ^ (row&7) on 16B groups keeps ds_read_b128
// 16B-aligned AND at the 8-cycle bank floor (odd halfword strides would
// misalign b128; unswizzled stride-192 would be a 16-way conflict).
// ---------------------------------------------------------------------------
#define ATSW(row, c)  ((row) * 128 + (((((c) >> 3) ^ ((row) & 7)) << 3) | ((c) & 7)))
#define EDSW(row, m)  ((row) * 192 + (((((m) >> 3) ^ ((row) & 7)) << 3) | ((m) & 7)))
#define SCSTR 204

__global__ __launch_bounds__(256) void k23_fused(const _Float16* __restrict__ xs,
                                                 const _Float16* __restrict__ Est,
                                                 _Float16* __restrict__ P) {
    const int h = blockIdx.x, b = blockIdx.y;
    const int t = threadIdx.x;
    const int lane = t & 63, wave = t >> 6;
    const int l15 = lane & 15, quad = lane >> 4;
    const int r0 = h * 96;

    __shared__ __align__(16) _Float16 EdL[192 * 192];   // 73,728 B
    __shared__ __align__(16) char UN[192 * 128 * 2];    // 49,152 B: At, then Sc
    _Float16* At = (_Float16*)UN;                       // [192 n][128 c] swizzled
    float*    Sc = (float*)UN;                          // [48][SCSTR] f32 (39,168 B)

    // ---- Stage At = xs[b]^T (zeros for n >= 170 via xs pad + explicit) ----
    const _Float16* __restrict__ xsb = xs + (size_t)b * NC * XSTR;
    #pragma unroll
    for (int it = 0; it < 12; ++it) {
        int g  = t + it * 256;         // [0, 3072); lanes of a wave share g>>7
        int gg = g >> 7;               // n-group [0,24)
        int c  = g & 127;
        int n0g = gg * 8;
        h8 v = {};
        if (n0g < XSTR)                // wave-uniform; rows 176..191 stay zero
            v = *reinterpret_cast<const h8*>(xsb + (size_t)c * XSTR + n0g);
        #pragma unroll
        for (int j = 0; j < 8; ++j)
            At[ATSW(n0g + j, c)] = v[j];
    }
    __syncthreads();

    // ---- GEMM1: wave w computes EdL rows [w*48, w*48+48) x all 192 m ----
    {
        h8 a[3][4];
        #pragma unroll
        for (int rt = 0; rt < 3; ++rt)
            #pragma unroll
            for (int kk = 0; kk < 4; ++kk) {
                int row = wave * 48 + rt * 16 + l15;
                int cg  = kk * 4 + quad;             // 16B c-group index
                a[rt][kk] = *reinterpret_cast<const h8*>(
                    &At[row * 128 + ((cg ^ (row & 7)) << 3)]);
            }
        #pragma unroll 2
        for (int ct = 0; ct < 12; ++ct) {
            h8 bfr[4];
            #pragma unroll
            for (int kk = 0; kk < 4; ++kk)
                bfr[kk] = *reinterpret_cast<const h8*>(
                    Est + (size_t)(ct * 16 + l15) * NC + kk * 32 + quad * 8);
            f4 acc1[3] = {};
            #pragma unroll
            for (int kk = 0; kk < 4; ++kk)
                #pragma unroll
                for (int rt = 0; rt < 3; ++rt)
                    acc1[rt] = __builtin_amdgcn_mfma_f32_16x16x32_f16(
                        a[rt][kk], bfr[kk], acc1[rt], 0, 0, 0);
            // epilogue: tanh -> EdL (b16 writes; pad rows/cols come out 0)
            #pragma unroll
            for (int rt = 0; rt < 3; ++rt)
                #pragma unroll
                for (int reg = 0; reg < 4; ++reg) {
                    int n = wave * 48 + rt * 16 + quad * 4 + reg;
                    int m = ct * 16 + l15;
                    EdL[EDSW(n, m)] = (_Float16)fast_tanh(acc1[rt][reg]);
                }
        }
    }
    __syncthreads();   // EdL complete; At dead from here (Sc may alias it)

    // ---- GEMM2: rows [r0, r0+96) x cols [0,192), K = 192 ----
    f4 acc2[6][3] = {};                              // 6 row-tiles x 3 col-tiles
    #pragma unroll
    for (int mc = 0; mc < 192; mc += 32) {
        h8 a2[6], b2[3];
        #pragma unroll
        for (int rt = 0; rt < 6; ++rt) {
            int row = r0 + rt * 16 + l15;
            int mg  = (mc >> 3) + quad;
            a2[rt] = *reinterpret_cast<const h8*>(
                &EdL[row * 192 + ((mg ^ (row & 7)) << 3)]);
        }
        #pragma unroll
        for (int ci = 0; ci < 3; ++ci) {
            int row = (wave * 3 + ci) * 16 + l15;    // score col base
            int mg  = (mc >> 3) + quad;
            b2[ci] = *reinterpret_cast<const h8*>(
                &EdL[row * 192 + ((mg ^ (row & 7)) << 3)]);
        }
        #pragma unroll
        for (int rt = 0; rt < 6; ++rt)
            #pragma unroll
            for (int ci = 0; ci < 3; ++ci)
                acc2[rt][ci] = __builtin_amdgcn_mfma_f32_16x16x32_f16(
                    a2[rt], b2[ci], acc2[rt][ci], 0, 0, 0);
    }

    // ---- scatter + softmax, two 48-row rounds (Sc fits the At alias) ----
    const float scale = 0.08838834764831845f;        // 1/sqrt(128)
    #pragma unroll
    for (int p = 0; p < 2; ++p) {
        __syncthreads();                             // Sc region safe to (re)use
        #pragma unroll
        for (int rt3 = 0; rt3 < 3; ++rt3) {
            int rt = p * 3 + rt3;
            #pragma unroll
            for (int ci = 0; ci < 3; ++ci) {
                int col = (wave * 3 + ci) * 16 + l15;
                #pragma unroll
                for (int reg = 0; reg < 4; ++reg) {
                    int rloc = rt3 * 16 + quad * 4 + reg;
                    Sc[rloc * SCSTR + col] = fmaxf(acc2[rt][ci][reg] * scale, 0.f);
                }
            }
        }
        __syncthreads();
        // softmax: wave owns rows wave*12 .. wave*12+11 of this 48-row round
        for (int rr = 0; rr < 12; ++rr) {
            int r = wave * 12 + rr;
            int n = r0 + p * 48 + r;
            if (n >= NN) continue;                   // wave-uniform
            float v0 = Sc[r * SCSTR + lane];
            float v1 = Sc[r * SCSTR + lane + 64];
            int  k2i = lane + 128;
            bool has2 = (k2i < NN);
            float v2 = has2 ? Sc[r * SCSTR + k2i] : -1.f;
            float m = fmaxf(fmaxf(v0, v1), v2);
            #pragma unroll
            for (int off = 32; off; off >>= 1) m = fmaxf(m, __shfl_xor(m, off, 64));
            float e0 = __expf(v0 - m);
            float e1 = __expf(v1 - m);
            float e2 = has2 ? __expf(v2 - m) : 0.f;
            float s = e0 + e1 + e2;
            #pragma unroll
            for (int off = 32; off; off >>= 1) s += __shfl_xor(s, off, 64);
            float inv = 1.f / s;
            _Float16* Pr = P + ((size_t)(b * NN + n)) * MP;
            Pr[lane]      = (_Float16)(e0 * inv);
            Pr[lane + 64] = (_Float16)(e1 * inv);
            if (has2) Pr[k2i] = (_Float16)(e2 * inv);
        }
    }
}

// ---------------------------------------------------------------------------
// K4: mean over batch + threshold in one pass (unchanged, proven).
// ---------------------------------------------------------------------------
__global__ __launch_bounds__(256) void k4_mean_thresh(const _Float16* __restrict__ P,
                                                      float* __restrict__ out) {
    int p = blockIdx.x * 256 + threadIdx.x;
    if (p >= NN * NN) return;
    int n = p / NN, k = p - n * NN;
    const _Float16* base = P + (size_t)n * MP + k;
    float s0 = 0.f, s1 = 0.f, s2 = 0.f, s3 = 0.f;
    #pragma unroll
    for (int b = 0; b < NB; b += 4) {
        s0 += (float)base[(size_t)(b + 0) * NN * MP];
        s1 += (float)base[(size_t)(b + 1) * NN * MP];
        s2 += (float)base[(size_t)(b + 2) * NN * MP];
        s3 += (float)base[(size_t)(b + 3) * NN * MP];
    }
    float s = (s0 + s1) + (s2 + s3);
    out[p] = (s * (1.f / 128.f) > 0.5f) ? 1.f : 0.f;
}

// ---------------------------------------------------------------------------
// Workspace layout (halfs):
//   [0, EST_SZ)   : Est (f16, [192][128])   live through K23
//   [+, +XS_SZ)   : xs  (f16, [b][c][176])  dead after K23
//   [+, +P_SZ)    : P   (f16, [b][n][176])  dead after K4
// Total = 13.5 MB.
// ---------------------------------------------------------------------------
extern "C" void kernel_launch(void* const* d_in, const int* in_sizes, int n_in,
                              void* d_out, int out_size, void* d_ws, size_t ws_size,
                              hipStream_t stream) {
    const float* x  = (const float*)d_in[0];   // [128,128,170,12] f32
    const float* Es = (const float*)d_in[1];   // [128,170] f32
    float* out = (float*)d_out;                // [170,170] f32

    _Float16* Est = (_Float16*)d_ws;
    _Float16* xs  = Est + EST_SZ;
    _Float16* P   = xs + XS_SZ;

    k1_tsum_est<<<5536, 256, 0, stream>>>(x, Es, xs, Est);
    k23_fused<<<dim3(2, 128), 256, 0, stream>>>(xs, Est, P);
    k4_mean_thresh<<<113, 256, 0, stream>>>(P, out);
}